// Round 12
// baseline (331.612 us; speedup 1.0000x reference)
//
#include <hip/hip_runtime.h>

#define NN 20000
#define NE 300000

typedef unsigned short u16;
typedef unsigned int   u32;

typedef __bf16 bf16x8 __attribute__((ext_vector_type(8)));
typedef float  f32x4  __attribute__((ext_vector_type(4)));

__device__ __forceinline__ float b2f(u16 u){ u32 x = ((u32)u) << 16; return __builtin_bit_cast(float, x); }
__device__ __forceinline__ u16 f2b(float f){
    u32 x = __builtin_bit_cast(u32, f);
    u32 r = x + 0x7fffu + ((x >> 16) & 1u);
    return (u16)(r >> 16);
}

__global__ void k_scan(const int* __restrict__ deg, int* __restrict__ offs, float* __restrict__ invd){
    __shared__ int part[1024];
    int t = threadIdx.x;
    int base = t * 20;
    int s = 0;
    for (int i = 0; i < 20; i++){ int idx = base + i; if (idx < NN) s += deg[idx]; }
    part[t] = s; __syncthreads();
    for (int d = 1; d < 1024; d <<= 1){
        int v = (t >= d) ? part[t - d] : 0;
        __syncthreads();
        part[t] += v;
        __syncthreads();
    }
    int run = part[t] - s;
    for (int i = 0; i < 20; i++){
        int idx = base + i;
        if (idx < NN){
            offs[idx] = run;
            int d0 = deg[idx];
            run += d0;
            invd[idx] = 1.0f / (float)(d0 > 0 ? d0 : 1);
        }
    }
    if (t == 1023) offs[NN] = part[1023];
}

// fills srcs (for layer1/aggr) and meta int4 {src, col, orig edge id, ea bits} (for k_edge)
__global__ void k_fill(const int* __restrict__ val, const int* __restrict__ key,
                       const float* __restrict__ ea, const int* __restrict__ offs,
                       int* __restrict__ cur, int* __restrict__ srcs, int4* __restrict__ meta){
    int e = blockIdx.x * 256 + threadIdx.x;
    if (e < NE){
        int c = key[e];
        if (c >= 0 && c < NN){
            int slot = offs[c] + atomicAdd(&cur[c], 1);
            int r = val[e];
            int sv = (r >= 0 && r < NN) ? r : 0;
            srcs[slot] = sv;
            int4 m;
            m.x = sv;
            m.y = c;
            m.z = e;
            m.w = __builtin_bit_cast(int, ea[e]);
            meta[slot] = m;
        }
    }
}

// ---------------- weight swizzles + degree count in ONE kernel (2836 blocks x 256) ----------------
// blocks [0,512): WLs2   [512,1024): WLs3   [1024,1536): Bcat   [1536,1664): B2s   [1664,2836): count
__global__ void k_swz_cnt(const float* __restrict__ Wl2, const float* __restrict__ Wr2,
                          const float* __restrict__ Wl3, const float* __restrict__ Wr3,
                          const float* __restrict__ W1,  const float* __restrict__ W2,
                          u16* __restrict__ WLs2, u16* __restrict__ WLs3,
                          u16* __restrict__ Bcat, u16* __restrict__ B2s,
                          const int* __restrict__ colv, int* __restrict__ deg){
    int b = blockIdx.x;
    if (b < 1024){
        const float* A = (b < 512) ? Wl2 : Wl3;
        const float* B = (b < 512) ? Wr2 : Wr3;
        u16* dst = (b < 512) ? WLs2 : WLs3;
        int t = (b & 511) * 256 + threadIdx.x;
        int j = t & 7, lane = (t >> 3) & 63, tile = t >> 9;
        int ktile = tile % 16, ntile = tile / 16;
        int k = ktile * 32 + ((lane >> 4) << 3) + j;
        int n = ntile * 16 + (lane & 15);
        dst[t] = f2b((k < 256) ? A[k * 256 + n] : B[(k - 256) * 256 + n]);
    } else if (b < 1536){
        int t = (b - 1024) * 256 + threadIdx.x;
        int j = t & 7, lane = (t >> 3) & 63, tile = t >> 9;
        int ktile = tile & 7, ntile = tile >> 3;
        int k = ktile * 32 + ((lane >> 4) << 3) + j;    // 0..255
        int n = ntile * 16 + (lane & 15);               // 0..511
        float v = (n < 256) ? W1[k * 256 + n] : W1[(256 + k) * 256 + (n - 256)];
        Bcat[t] = f2b(v);
    } else if (b < 1664){
        int t = (b - 1536) * 256 + threadIdx.x;
        int j = t & 7, lane = (t >> 3) & 63, tile = t >> 9;
        int ktile = tile % 8, ntile = tile / 8;
        int k = ktile * 32 + ((lane >> 4) << 3) + j;
        int n = ntile * 16 + (lane & 15);
        B2s[t] = f2b(W2[k * 128 + n]);
    } else {
        int e = (b - 1664) * 256 + threadIdx.x;
        if (e < NE){
            int c = colv[e];
            if (c >= 0 && c < NN) atomicAdd(&deg[c], 1);
        }
    }
}

// ---------------- SAGE layer 1 (din=3): fp32 math, bf16 output ----------------
__global__ void k_layer1(const float* __restrict__ x, const int* __restrict__ offs, const int* __restrict__ srcs,
                         const float* __restrict__ invd, const float* __restrict__ Wl, const float* __restrict__ bl,
                         const float* __restrict__ Wr, u16* __restrict__ h1){
    int node = blockIdx.x * 4 + (threadIdx.x >> 6);
    int lane = threadIdx.x & 63;
    int st = offs[node], en = offs[node + 1];
    float s0 = 0.f, s1 = 0.f, s2 = 0.f;
    for (int j = st + lane; j < en; j += 64){
        int s = srcs[j];
        s0 += x[s * 3 + 0]; s1 += x[s * 3 + 1]; s2 += x[s * 3 + 2];
    }
    #pragma unroll
    for (int d = 1; d < 64; d <<= 1){
        s0 += __shfl_xor(s0, d); s1 += __shfl_xor(s1, d); s2 += __shfl_xor(s2, d);
    }
    float inv = invd[node];
    float a0 = s0 * inv, a1 = s1 * inv, a2 = s2 * inv;
    float xi0 = x[node * 3 + 0], xi1 = x[node * 3 + 1], xi2 = x[node * 3 + 2];
    int f0 = lane * 4;
    ushort4 stv;
    u16* sp = (u16*)&stv;
    #pragma unroll
    for (int r = 0; r < 4; r++){
        int n = f0 + r;
        float o = a0 * Wl[n] + a1 * Wl[256 + n] + a2 * Wl[512 + n]
                + xi0 * Wr[n] + xi1 * Wr[256 + n] + xi2 * Wr[512 + n] + bl[n];
        sp[r] = f2b(o > 0.f ? o : 0.f);
    }
    *(ushort4*)(h1 + node * 256 + f0) = stv;
}

// ---------------- mean aggregation over CSR: 4 rows in flight per wave (round-8 proven, high TLP) ----------------
__global__ void k_aggr(const u16* __restrict__ hin, const int* __restrict__ offs, const int* __restrict__ srcs,
                       const float* __restrict__ invd, u16* __restrict__ aggr){
    int node = blockIdx.x * 4 + (threadIdx.x >> 6);
    int lane = threadIdx.x & 63;
    int st = offs[node], en = offs[node + 1];
    int q = lane >> 4;            // 0..3: row-group (4 edges in flight)
    int c0 = (lane & 15) * 16;    // u16 units: 16 bf16 per lane
    float a[16];
    #pragma unroll
    for (int i = 0; i < 16; i++) a[i] = 0.f;
    for (int j = st + q; j < en; j += 4){
        int s = srcs[j];
        const u16* hp = hin + s * 256 + c0;
        uint4 v0 = *(const uint4*)(hp);
        uint4 v1 = *(const uint4*)(hp + 8);
        a[0]  += b2f((u16)v0.x); a[1]  += b2f((u16)(v0.x >> 16));
        a[2]  += b2f((u16)v0.y); a[3]  += b2f((u16)(v0.y >> 16));
        a[4]  += b2f((u16)v0.z); a[5]  += b2f((u16)(v0.z >> 16));
        a[6]  += b2f((u16)v0.w); a[7]  += b2f((u16)(v0.w >> 16));
        a[8]  += b2f((u16)v1.x); a[9]  += b2f((u16)(v1.x >> 16));
        a[10] += b2f((u16)v1.y); a[11] += b2f((u16)(v1.y >> 16));
        a[12] += b2f((u16)v1.z); a[13] += b2f((u16)(v1.z >> 16));
        a[14] += b2f((u16)v1.w); a[15] += b2f((u16)(v1.w >> 16));
    }
    #pragma unroll
    for (int i = 0; i < 16; i++){
        a[i] += __shfl_xor(a[i], 16);
        a[i] += __shfl_xor(a[i], 32);
    }
    if (q == 0){
        float inv = invd[node];
        uint4 o0, o1;
        o0.x = (u32)f2b(a[0]  * inv) | ((u32)f2b(a[1]  * inv) << 16);
        o0.y = (u32)f2b(a[2]  * inv) | ((u32)f2b(a[3]  * inv) << 16);
        o0.z = (u32)f2b(a[4]  * inv) | ((u32)f2b(a[5]  * inv) << 16);
        o0.w = (u32)f2b(a[6]  * inv) | ((u32)f2b(a[7]  * inv) << 16);
        o1.x = (u32)f2b(a[8]  * inv) | ((u32)f2b(a[9]  * inv) << 16);
        o1.y = (u32)f2b(a[10] * inv) | ((u32)f2b(a[11] * inv) << 16);
        o1.z = (u32)f2b(a[12] * inv) | ((u32)f2b(a[13] * inv) << 16);
        o1.w = (u32)f2b(a[14] * inv) | ((u32)f2b(a[15] * inv) << 16);
        *(uint4*)(aggr + node * 256 + c0) = o0;
        *(uint4*)(aggr + node * 256 + c0 + 8) = o1;
    }
}

// ---------------- node dense layer: relu([aggr|hin] @ Bs + bias), N-split (313,2) ----------------
// Barrier-free: B-fragments loaded per-wave directly from L2 (table is 256 KB, L2-resident).
// No LDS, no __syncthreads -> waves stream 128 MFMAs independently. Bit-identical math.
__global__ __launch_bounds__(256) void k_gemm_node(const u16* __restrict__ aggr, const u16* __restrict__ hin,
    const u16* __restrict__ Bs, const float* __restrict__ bias, u16* __restrict__ out){
    int t = threadIdx.x, wave = t >> 6, lane = t & 63;
    int m0 = blockIdx.x * 64 + wave * 16;
    int nb = blockIdx.y * 8;                   // global ntile base (8 ntiles = 128 cols)
    int ml = lane & 15, g = lane >> 4;
    int arow = m0 + ml; if (arow > NN - 1) arow = NN - 1;
    const u16* pa = aggr + (size_t)arow * 256;
    const u16* ph = hin  + (size_t)arow * 256;
    const u16* pb = Bs + (size_t)nb * 16 * 512 + lane * 8;   // + (nt*16 + k32)*512 per fragment

    f32x4 acc[8] = {};
    for (int k32 = 0; k32 < 16; k32++){
        const u16* asrc = (k32 < 8) ? (pa + k32 * 32) : (ph + (k32 - 8) * 32);
        bf16x8 af = __builtin_bit_cast(bf16x8, *(const uint4*)(asrc + g * 8));
        const u16* pbk = pb + k32 * 512;
        #pragma unroll
        for (int nt = 0; nt < 8; nt++){
            bf16x8 bfr = __builtin_bit_cast(bf16x8, *(const uint4*)(pbk + nt * 8192));
            acc[nt] = __builtin_amdgcn_mfma_f32_16x16x32_bf16(af, bfr, acc[nt], 0, 0, 0);
        }
    }
    #pragma unroll
    for (int nt = 0; nt < 8; nt++){
        int n = (nb + nt) * 16 + ml;
        float bn = bias[n];
        #pragma unroll
        for (int r = 0; r < 4; r++){
            int rowg = m0 + g * 4 + r;
            if (rowg < NN){
                float v = acc[nt][r] + bn;
                out[(size_t)rowg * 256 + n] = f2b(v > 0.f ? v : 0.f);
            }
        }
    }
}

// ---------------- node-level P GEMM: P = bf16( h@[W1a|W1b] + base ), barrier-free direct-B ----------------
__global__ __launch_bounds__(256) void k_gemm_p(const u16* __restrict__ hin,
    const u16* __restrict__ Bc, const float* __restrict__ b1, const float* __restrict__ W1tail,
    const float* __restrict__ tdp, u16* __restrict__ P){
    int t = threadIdx.x, wave = t >> 6, lane = t & 63;
    int m0 = blockIdx.x * 64 + wave * 16;
    int nb = blockIdx.y * 8;                   // global ntile base (0..31 total)
    int ml = lane & 15, g = lane >> 4;
    int arow = m0 + ml; if (arow > NN - 1) arow = NN - 1;
    const u16* ph = hin + (size_t)arow * 256;
    const u16* pb = Bc + (size_t)nb * 8 * 512 + lane * 8;    // + (nt*8 + k32)*512 per fragment
    float td = tdp[0];

    f32x4 acc[8] = {};
    for (int k32 = 0; k32 < 8; k32++){
        bf16x8 af = __builtin_bit_cast(bf16x8, *(const uint4*)(ph + k32 * 32 + g * 8));
        const u16* pbk = pb + k32 * 512;
        #pragma unroll
        for (int nt = 0; nt < 8; nt++){
            bf16x8 bfr = __builtin_bit_cast(bf16x8, *(const uint4*)(pbk + nt * 4096));
            acc[nt] = __builtin_amdgcn_mfma_f32_16x16x32_bf16(af, bfr, acc[nt], 0, 0, 0);
        }
    }
    #pragma unroll
    for (int nt = 0; nt < 8; nt++){
        int n = (nb + nt) * 16 + ml;                       // 0..511
        float base = (n < 256) ? (b1[n] + td * W1tail[256 + n]) : 0.f;
        #pragma unroll
        for (int r = 0; r < 4; r++){
            int rowg = m0 + g * 4 + r;
            if (rowg < NN) P[(size_t)rowg * 512 + n] = f2b(acc[nt][r] + base);
        }
    }
}

// ---------------- edge kernel (CSR-ordered, bf16 P): z1 = relu(Pa[src]+Pb[col]+ea*w512) -> GEMM2 -> W3 dot ----------------
__global__ __launch_bounds__(256) void k_edge(const u16* __restrict__ P,
    const int4* __restrict__ meta, const float* __restrict__ W1tail,
    const u16* __restrict__ B2s, const float* __restrict__ b2v,
    const float* __restrict__ W3, const float* __restrict__ b3, float* __restrict__ out){
    __shared__ __align__(16) u16 ldsX[4096];    // 8 KB: one B2 k32-chunk
    __shared__ __align__(16) u16 ldsZ[16384];   // 32 KB: z1, per-wave 16 x 256, xor-swizzled
    int t = threadIdx.x, wave = t >> 6, lane = t & 63;
    int m0 = blockIdx.x * 64;
    int half = lane >> 5, cl = lane & 31;
    int c0 = cl * 8;

    float wv[8];
    #pragma unroll
    for (int j = 0; j < 8; j++) wv[j] = W1tail[c0 + j];

    #pragma unroll
    for (int it = 0; it < 8; it += 2){
        int rA = it * 2 + half;
        int rB = it * 2 + 2 + half;
        int sA = m0 + wave * 16 + rA; if (sA > NE - 1) sA = NE - 1;
        int sB = m0 + wave * 16 + rB; if (sB > NE - 1) sB = NE - 1;
        int4 mA = meta[sA];
        int4 mB = meta[sB];
        const u16* paA = P + (size_t)mA.x * 512;
        const u16* pbA = P + (size_t)mA.y * 512 + 256;
        const u16* paB = P + (size_t)mB.x * 512;
        const u16* pbB = P + (size_t)mB.y * 512 + 256;
        float eA = __builtin_bit_cast(float, mA.w);
        float eB = __builtin_bit_cast(float, mB.w);
        uint4 vaA = *(const uint4*)(paA + c0);
        uint4 vbA = *(const uint4*)(pbA + c0);
        uint4 vaB = *(const uint4*)(paB + c0);
        uint4 vbB = *(const uint4*)(pbB + c0);
        float v0, v1, v2, v3, v4, v5, v6, v7;
        uint4 st;
        v0 = b2f((u16)vaA.x) + b2f((u16)vbA.x) + eA * wv[0];
        v1 = b2f((u16)(vaA.x >> 16)) + b2f((u16)(vbA.x >> 16)) + eA * wv[1];
        v2 = b2f((u16)vaA.y) + b2f((u16)vbA.y) + eA * wv[2];
        v3 = b2f((u16)(vaA.y >> 16)) + b2f((u16)(vbA.y >> 16)) + eA * wv[3];
        v4 = b2f((u16)vaA.z) + b2f((u16)vbA.z) + eA * wv[4];
        v5 = b2f((u16)(vaA.z >> 16)) + b2f((u16)(vbA.z >> 16)) + eA * wv[5];
        v6 = b2f((u16)vaA.w) + b2f((u16)vbA.w) + eA * wv[6];
        v7 = b2f((u16)(vaA.w >> 16)) + b2f((u16)(vbA.w >> 16)) + eA * wv[7];
        v0 = v0 > 0.f ? v0 : 0.f; v1 = v1 > 0.f ? v1 : 0.f;
        v2 = v2 > 0.f ? v2 : 0.f; v3 = v3 > 0.f ? v3 : 0.f;
        v4 = v4 > 0.f ? v4 : 0.f; v5 = v5 > 0.f ? v5 : 0.f;
        v6 = v6 > 0.f ? v6 : 0.f; v7 = v7 > 0.f ? v7 : 0.f;
        st.x = (u32)f2b(v0) | ((u32)f2b(v1) << 16);
        st.y = (u32)f2b(v2) | ((u32)f2b(v3) << 16);
        st.z = (u32)f2b(v4) | ((u32)f2b(v5) << 16);
        st.w = (u32)f2b(v6) | ((u32)f2b(v7) << 16);
        *(uint4*)(&ldsZ[wave * 4096 + rA * 256 + ((cl ^ (rA & 7)) << 3)]) = st;
        v0 = b2f((u16)vaB.x) + b2f((u16)vbB.x) + eB * wv[0];
        v1 = b2f((u16)(vaB.x >> 16)) + b2f((u16)(vbB.x >> 16)) + eB * wv[1];
        v2 = b2f((u16)vaB.y) + b2f((u16)vbB.y) + eB * wv[2];
        v3 = b2f((u16)(vaB.y >> 16)) + b2f((u16)(vbB.y >> 16)) + eB * wv[3];
        v4 = b2f((u16)vaB.z) + b2f((u16)vbB.z) + eB * wv[4];
        v5 = b2f((u16)(vaB.z >> 16)) + b2f((u16)(vbB.z >> 16)) + eB * wv[5];
        v6 = b2f((u16)vaB.w) + b2f((u16)vbB.w) + eB * wv[6];
        v7 = b2f((u16)(vaB.w >> 16)) + b2f((u16)(vbB.w >> 16)) + eB * wv[7];
        v0 = v0 > 0.f ? v0 : 0.f; v1 = v1 > 0.f ? v1 : 0.f;
        v2 = v2 > 0.f ? v2 : 0.f; v3 = v3 > 0.f ? v3 : 0.f;
        v4 = v4 > 0.f ? v4 : 0.f; v5 = v5 > 0.f ? v5 : 0.f;
        v6 = v6 > 0.f ? v6 : 0.f; v7 = v7 > 0.f ? v7 : 0.f;
        st.x = (u32)f2b(v0) | ((u32)f2b(v1) << 16);
        st.y = (u32)f2b(v2) | ((u32)f2b(v3) << 16);
        st.z = (u32)f2b(v4) | ((u32)f2b(v5) << 16);
        st.w = (u32)f2b(v6) | ((u32)f2b(v7) << 16);
        *(uint4*)(&ldsZ[wave * 4096 + rB * 256 + ((cl ^ (rB & 7)) << 3)]) = st;
    }

    int ml = lane & 15, g = lane >> 4;
    int nt0 = t >> 6, off0 = (t & 63) * 8;
    f32x4 acc2[8] = {};
    uint4 q0 = *(const uint4*)(B2s + (nt0 * 8 + 0) * 512 + off0);
    uint4 q1 = *(const uint4*)(B2s + ((nt0 + 4) * 8 + 0) * 512 + off0);
    for (int kc = 0; kc < 8; kc++){
        __syncthreads();
        *(uint4*)(&ldsX[nt0 * 512 + off0]) = q0;
        *(uint4*)(&ldsX[(nt0 + 4) * 512 + off0]) = q1;
        if (kc < 7){
            q0 = *(const uint4*)(B2s + (nt0 * 8 + kc + 1) * 512 + off0);
            q1 = *(const uint4*)(B2s + ((nt0 + 4) * 8 + kc + 1) * 512 + off0);
        }
        __syncthreads();
        int kb = kc * 4 + g;
        bf16x8 af = __builtin_bit_cast(bf16x8, *(const uint4*)(&ldsZ[wave * 4096 + ml * 256 + ((kb ^ (ml & 7)) << 3)]));
        #pragma unroll
        for (int nt = 0; nt < 8; nt++){
            bf16x8 bfr = __builtin_bit_cast(bf16x8, *(const uint4*)(&ldsX[(nt * 64 + lane) * 8]));
            acc2[nt] = __builtin_amdgcn_mfma_f32_16x16x32_bf16(af, bfr, acc2[nt], 0, 0, 0);
        }
    }
    float s0 = 0.f, s1 = 0.f, s2 = 0.f, s3 = 0.f;
    #pragma unroll
    for (int nt = 0; nt < 8; nt++){
        int n = nt * 16 + ml;
        float bn = b2v[n];
        float w3 = W3[n];
        float z;
        z = acc2[nt][0] + bn; s0 += (z > 0.f ? z : 0.f) * w3;
        z = acc2[nt][1] + bn; s1 += (z > 0.f ? z : 0.f) * w3;
        z = acc2[nt][2] + bn; s2 += (z > 0.f ? z : 0.f) * w3;
        z = acc2[nt][3] + bn; s3 += (z > 0.f ? z : 0.f) * w3;
    }
    #pragma unroll
    for (int d = 1; d < 16; d <<= 1){
        s0 += __shfl_xor(s0, d); s1 += __shfl_xor(s1, d);
        s2 += __shfl_xor(s2, d); s3 += __shfl_xor(s3, d);
    }
    if (ml == 0){
        float bb = b3[0];
        int sb = m0 + wave * 16 + g * 4;
        const int* mz = (const int*)meta;
        if (sb + 0 < NE) out[mz[(sb + 0) * 4 + 2]] = s0 + bb;
        if (sb + 1 < NE) out[mz[(sb + 1) * 4 + 2]] = s1 + bb;
        if (sb + 2 < NE) out[mz[(sb + 2) * 4 + 2]] = s2 + bb;
        if (sb + 3 < NE) out[mz[(sb + 3) * 4 + 2]] = s3 + bb;
    }
}

__global__ void k_fillcode_f32(float* __restrict__ out, float c){
    int i = blockIdx.x * 256 + threadIdx.x;
    if (i < NE) out[i] = c;
}

extern "C" void kernel_launch(void* const* d_in, const int* in_sizes, int n_in,
                              void* d_out, int out_size, void* d_ws, size_t ws_size,
                              hipStream_t stream){
    float* out = (float*)d_out;

    static const int exp_sizes[19] = {60000,600000,300000,1,768,256,768,65536,256,65536,
                                      65536,256,65536,131584,256,32768,128,128,1};
    int bad = -1;
    if (n_in != 19) bad = 19;
    else for (int k = 0; k < 19; k++) if (in_sizes[k] != exp_sizes[k]){ bad = k; break; }
    if (bad >= 0){
        k_fillcode_f32<<<(NE + 255) / 256, 256, 0, stream>>>(out, 1000.f + 50.f * bad);
        return;
    }

    char* ws = (char*)d_ws;
    size_t off = 0;
    auto alloc = [&](size_t bytes) -> void* {
        void* p = ws + off;
        off += (bytes + 255) & ~(size_t)255;
        return p;
    };
    int*   deg   = (int*)alloc(NN * 4);
    int*   cur   = (int*)alloc(NN * 4);
    int*   offs  = (int*)alloc((NN + 1) * 4);
    float* invd  = (float*)alloc(NN * 4);
    int*   srcs  = (int*)alloc(NE * 4);
    int4*  meta  = (int4*)alloc((size_t)NE * 16);
    u16*   h1b   = (u16*)alloc((size_t)NN * 256 * 2);
    u16*   h2b   = (u16*)alloc((size_t)NN * 256 * 2);
    u16*   h3b   = (u16*)alloc((size_t)NN * 256 * 2);
    u16*   aggb  = (u16*)alloc((size_t)NN * 256 * 2);
    u16*   WLs2  = (u16*)alloc(512 * 256 * 2);
    u16*   WLs3  = (u16*)alloc(512 * 256 * 2);
    u16*   Bcat  = (u16*)alloc(512 * 256 * 2);
    u16*   B2s   = (u16*)alloc(256 * 128 * 2);
    u16*   Pbuf  = (u16*)alloc((size_t)NN * 512 * 2);   // 20.5 MB: [Pa|Pb] bf16
    if (off > ws_size){
        k_fillcode_f32<<<(NE + 255) / 256, 256, 0, stream>>>(out, 9000.f);
        return;
    }

    const float* x   = (const float*)d_in[0];
    const int*   ei  = (const int*)d_in[1];     // (2,E) int32: [row..., col...]
    const float* ea  = (const float*)d_in[2];
    const float* td  = (const float*)d_in[3];
    const float* Wl1 = (const float*)d_in[4];
    const float* bl1 = (const float*)d_in[5];
    const float* Wr1 = (const float*)d_in[6];
    const float* Wl2 = (const float*)d_in[7];
    const float* bl2 = (const float*)d_in[8];
    const float* Wr2 = (const float*)d_in[9];
    const float* Wl3 = (const float*)d_in[10];
    const float* bl3 = (const float*)d_in[11];
    const float* Wr3 = (const float*)d_in[12];
    const float* W1  = (const float*)d_in[13];
    const float* b1  = (const float*)d_in[14];
    const float* W2  = (const float*)d_in[15];
    const float* b2  = (const float*)d_in[16];
    const float* W3  = (const float*)d_in[17];
    const float* b3  = (const float*)d_in[18];

    hipMemsetAsync(deg, 0, (size_t)((char*)cur - (char*)deg) + NN * 4, stream);

    const int* rowv = ei;          // sources
    const int* colv = ei + NE;     // targets

    // weight swizzles + degree count in one launch (count needs the memset above)
    k_swz_cnt<<<2836, 256, 0, stream>>>(Wl2, Wr2, Wl3, Wr3, W1, W2, WLs2, WLs3, Bcat, B2s, colv, deg);
    k_scan <<<1, 1024, 0, stream>>>(deg, offs, invd);
    k_fill <<<(NE + 255) / 256, 256, 0, stream>>>(rowv, colv, ea, offs, cur, srcs, meta);

    // SAGE layer 1 (fp32 math, bf16 out)
    k_layer1<<<NN / 4, 256, 0, stream>>>(x, offs, srcs, invd, Wl1, bl1, Wr1, h1b);

    dim3 ggrid((NN + 63) / 64, 2);

    // SAGE layers 2,3: high-TLP aggr + barrier-free direct-B GEMM
    k_aggr<<<NN / 4, 256, 0, stream>>>(h1b, offs, srcs, invd, aggb);
    k_gemm_node<<<ggrid, 256, 0, stream>>>(aggb, h1b, WLs2, bl2, h2b);

    k_aggr<<<NN / 4, 256, 0, stream>>>(h2b, offs, srcs, invd, aggb);
    k_gemm_node<<<ggrid, 256, 0, stream>>>(aggb, h2b, WLs3, bl3, h3b);

    // node-level P = bf16(h3 @ [W1a|W1b] + base), barrier-free direct-B
    dim3 pgrid((NN + 63) / 64, 4);
    k_gemm_p<<<pgrid, 256, 0, stream>>>(h3b, Bcat, b1, W1 + 512 * 256, td, Pbuf);

    // edge kernel (CSR order, 64 edges/block, bf16 P)
    k_edge<<<(NE + 63) / 64, 256, 0, stream>>>(Pbuf, meta, W1 + 512 * 256,
                                               B2s, b2, W3, b3, out);
}

// Round 13
// 315.369 us; speedup vs baseline: 1.0515x; 1.0515x over previous
//
#include <hip/hip_runtime.h>

#define NN 20000
#define NE 300000

typedef unsigned short u16;
typedef unsigned int   u32;

typedef __bf16 bf16x8 __attribute__((ext_vector_type(8)));
typedef float  f32x4  __attribute__((ext_vector_type(4)));

__device__ __forceinline__ float b2f(u16 u){ u32 x = ((u32)u) << 16; return __builtin_bit_cast(float, x); }
__device__ __forceinline__ u16 f2b(float f){
    u32 x = __builtin_bit_cast(u32, f);
    u32 r = x + 0x7fffu + ((x >> 16) & 1u);
    return (u16)(r >> 16);
}

__global__ void k_scan(const int* __restrict__ deg, int* __restrict__ offs, float* __restrict__ invd){
    __shared__ int part[1024];
    int t = threadIdx.x;
    int base = t * 20;
    int s = 0;
    for (int i = 0; i < 20; i++){ int idx = base + i; if (idx < NN) s += deg[idx]; }
    part[t] = s; __syncthreads();
    for (int d = 1; d < 1024; d <<= 1){
        int v = (t >= d) ? part[t - d] : 0;
        __syncthreads();
        part[t] += v;
        __syncthreads();
    }
    int run = part[t] - s;
    for (int i = 0; i < 20; i++){
        int idx = base + i;
        if (idx < NN){
            offs[idx] = run;
            int d0 = deg[idx];
            run += d0;
            invd[idx] = 1.0f / (float)(d0 > 0 ? d0 : 1);
        }
    }
    if (t == 1023) offs[NN] = part[1023];
}

// fills srcs (for layer1/aggr) and meta int4 {src, col, orig edge id, ea bits} (for k_edge)
__global__ void k_fill(const int* __restrict__ val, const int* __restrict__ key,
                       const float* __restrict__ ea, const int* __restrict__ offs,
                       int* __restrict__ cur, int* __restrict__ srcs, int4* __restrict__ meta){
    int e = blockIdx.x * 256 + threadIdx.x;
    if (e < NE){
        int c = key[e];
        if (c >= 0 && c < NN){
            int slot = offs[c] + atomicAdd(&cur[c], 1);
            int r = val[e];
            int sv = (r >= 0 && r < NN) ? r : 0;
            srcs[slot] = sv;
            int4 m;
            m.x = sv;
            m.y = c;
            m.z = e;
            m.w = __builtin_bit_cast(int, ea[e]);
            meta[slot] = m;
        }
    }
}

// ---------------- weight swizzles + degree count in ONE kernel (2836 blocks x 256) ----------------
// blocks [0,512): WLs2   [512,1024): WLs3   [1024,1536): Bcat   [1536,1664): B2s   [1664,2836): count
__global__ void k_swz_cnt(const float* __restrict__ Wl2, const float* __restrict__ Wr2,
                          const float* __restrict__ Wl3, const float* __restrict__ Wr3,
                          const float* __restrict__ W1,  const float* __restrict__ W2,
                          u16* __restrict__ WLs2, u16* __restrict__ WLs3,
                          u16* __restrict__ Bcat, u16* __restrict__ B2s,
                          const int* __restrict__ colv, int* __restrict__ deg){
    int b = blockIdx.x;
    if (b < 1024){
        const float* A = (b < 512) ? Wl2 : Wl3;
        const float* B = (b < 512) ? Wr2 : Wr3;
        u16* dst = (b < 512) ? WLs2 : WLs3;
        int t = (b & 511) * 256 + threadIdx.x;
        int j = t & 7, lane = (t >> 3) & 63, tile = t >> 9;
        int ktile = tile % 16, ntile = tile / 16;
        int k = ktile * 32 + ((lane >> 4) << 3) + j;
        int n = ntile * 16 + (lane & 15);
        dst[t] = f2b((k < 256) ? A[k * 256 + n] : B[(k - 256) * 256 + n]);
    } else if (b < 1536){
        int t = (b - 1024) * 256 + threadIdx.x;
        int j = t & 7, lane = (t >> 3) & 63, tile = t >> 9;
        int ktile = tile & 7, ntile = tile >> 3;
        int k = ktile * 32 + ((lane >> 4) << 3) + j;    // 0..255
        int n = ntile * 16 + (lane & 15);               // 0..511
        float v = (n < 256) ? W1[k * 256 + n] : W1[(256 + k) * 256 + (n - 256)];
        Bcat[t] = f2b(v);
    } else if (b < 1664){
        int t = (b - 1536) * 256 + threadIdx.x;
        int j = t & 7, lane = (t >> 3) & 63, tile = t >> 9;
        int ktile = tile % 8, ntile = tile / 8;
        int k = ktile * 32 + ((lane >> 4) << 3) + j;
        int n = ntile * 16 + (lane & 15);
        B2s[t] = f2b(W2[k * 128 + n]);
    } else {
        int e = (b - 1664) * 256 + threadIdx.x;
        if (e < NE){
            int c = colv[e];
            if (c >= 0 && c < NN) atomicAdd(&deg[c], 1);
        }
    }
}

// ---------------- SAGE layer 1 (din=3): fp32 math, bf16 output ----------------
__global__ void k_layer1(const float* __restrict__ x, const int* __restrict__ offs, const int* __restrict__ srcs,
                         const float* __restrict__ invd, const float* __restrict__ Wl, const float* __restrict__ bl,
                         const float* __restrict__ Wr, u16* __restrict__ h1){
    int node = blockIdx.x * 4 + (threadIdx.x >> 6);
    int lane = threadIdx.x & 63;
    int st = offs[node], en = offs[node + 1];
    float s0 = 0.f, s1 = 0.f, s2 = 0.f;
    for (int j = st + lane; j < en; j += 64){
        int s = srcs[j];
        s0 += x[s * 3 + 0]; s1 += x[s * 3 + 1]; s2 += x[s * 3 + 2];
    }
    #pragma unroll
    for (int d = 1; d < 64; d <<= 1){
        s0 += __shfl_xor(s0, d); s1 += __shfl_xor(s1, d); s2 += __shfl_xor(s2, d);
    }
    float inv = invd[node];
    float a0 = s0 * inv, a1 = s1 * inv, a2 = s2 * inv;
    float xi0 = x[node * 3 + 0], xi1 = x[node * 3 + 1], xi2 = x[node * 3 + 2];
    int f0 = lane * 4;
    ushort4 stv;
    u16* sp = (u16*)&stv;
    #pragma unroll
    for (int r = 0; r < 4; r++){
        int n = f0 + r;
        float o = a0 * Wl[n] + a1 * Wl[256 + n] + a2 * Wl[512 + n]
                + xi0 * Wr[n] + xi1 * Wr[256 + n] + xi2 * Wr[512 + n] + bl[n];
        sp[r] = f2b(o > 0.f ? o : 0.f);
    }
    *(ushort4*)(h1 + node * 256 + f0) = stv;
}

// ---------------- mean aggregation over CSR: 4 rows in flight per wave (round-8 proven, high TLP) ----------------
__global__ void k_aggr(const u16* __restrict__ hin, const int* __restrict__ offs, const int* __restrict__ srcs,
                       const float* __restrict__ invd, u16* __restrict__ aggr){
    int node = blockIdx.x * 4 + (threadIdx.x >> 6);
    int lane = threadIdx.x & 63;
    int st = offs[node], en = offs[node + 1];
    int q = lane >> 4;            // 0..3: row-group (4 edges in flight)
    int c0 = (lane & 15) * 16;    // u16 units: 16 bf16 per lane
    float a[16];
    #pragma unroll
    for (int i = 0; i < 16; i++) a[i] = 0.f;
    for (int j = st + q; j < en; j += 4){
        int s = srcs[j];
        const u16* hp = hin + s * 256 + c0;
        uint4 v0 = *(const uint4*)(hp);
        uint4 v1 = *(const uint4*)(hp + 8);
        a[0]  += b2f((u16)v0.x); a[1]  += b2f((u16)(v0.x >> 16));
        a[2]  += b2f((u16)v0.y); a[3]  += b2f((u16)(v0.y >> 16));
        a[4]  += b2f((u16)v0.z); a[5]  += b2f((u16)(v0.z >> 16));
        a[6]  += b2f((u16)v0.w); a[7]  += b2f((u16)(v0.w >> 16));
        a[8]  += b2f((u16)v1.x); a[9]  += b2f((u16)(v1.x >> 16));
        a[10] += b2f((u16)v1.y); a[11] += b2f((u16)(v1.y >> 16));
        a[12] += b2f((u16)v1.z); a[13] += b2f((u16)(v1.z >> 16));
        a[14] += b2f((u16)v1.w); a[15] += b2f((u16)(v1.w >> 16));
    }
    #pragma unroll
    for (int i = 0; i < 16; i++){
        a[i] += __shfl_xor(a[i], 16);
        a[i] += __shfl_xor(a[i], 32);
    }
    if (q == 0){
        float inv = invd[node];
        uint4 o0, o1;
        o0.x = (u32)f2b(a[0]  * inv) | ((u32)f2b(a[1]  * inv) << 16);
        o0.y = (u32)f2b(a[2]  * inv) | ((u32)f2b(a[3]  * inv) << 16);
        o0.z = (u32)f2b(a[4]  * inv) | ((u32)f2b(a[5]  * inv) << 16);
        o0.w = (u32)f2b(a[6]  * inv) | ((u32)f2b(a[7]  * inv) << 16);
        o1.x = (u32)f2b(a[8]  * inv) | ((u32)f2b(a[9]  * inv) << 16);
        o1.y = (u32)f2b(a[10] * inv) | ((u32)f2b(a[11] * inv) << 16);
        o1.z = (u32)f2b(a[12] * inv) | ((u32)f2b(a[13] * inv) << 16);
        o1.w = (u32)f2b(a[14] * inv) | ((u32)f2b(a[15] * inv) << 16);
        *(uint4*)(aggr + node * 256 + c0) = o0;
        *(uint4*)(aggr + node * 256 + c0 + 8) = o1;
    }
}

// ---------------- node dense layer: relu([aggr|hin] @ Bs + bias), MFMA, N-split grid (313,2) ----------------
// Round-11 proven LDS-staged version (318.0 us config): cross-wave B-reuse via 8 KB LDS,
// 626 blocks keep latency hidden. Direct-B (r12) measured ~5-8 us slower; full-N (r10) -60 us.
__global__ __launch_bounds__(256) void k_gemm_node(const u16* __restrict__ aggr, const u16* __restrict__ hin,
    const u16* __restrict__ Bs, const float* __restrict__ bias, u16* __restrict__ out){
    __shared__ __align__(16) u16 ldsB[4096];   // 8 KB: one k32-chunk, 8 local ntiles
    int t = threadIdx.x, wave = t >> 6, lane = t & 63;
    int m0 = blockIdx.x * 64 + wave * 16;
    int nb = blockIdx.y * 8;                   // global ntile base (8 ntiles = 128 cols)
    int ml = lane & 15, g = lane >> 4;
    int arow = m0 + ml; if (arow > NN - 1) arow = NN - 1;
    const u16* pa = aggr + (size_t)arow * 256;
    const u16* ph = hin  + (size_t)arow * 256;

    int flat0 = t * 8, flat1 = (256 + t) * 8;
    int s0i = flat0 >> 9, o0 = flat0 & 511;    // local ntile 0..3
    int s1i = flat1 >> 9, o1 = flat1 & 511;    // local ntile 4..7
    uint4 p0 = *(const uint4*)(Bs + ((nb + s0i) * 16 + 0) * 512 + o0);
    uint4 p1 = *(const uint4*)(Bs + ((nb + s1i) * 16 + 0) * 512 + o1);

    f32x4 acc[8] = {};
    for (int k32 = 0; k32 < 16; k32++){
        __syncthreads();
        *(uint4*)(&ldsB[s0i * 512 + o0]) = p0;
        *(uint4*)(&ldsB[s1i * 512 + o1]) = p1;
        if (k32 < 15){
            p0 = *(const uint4*)(Bs + ((nb + s0i) * 16 + k32 + 1) * 512 + o0);
            p1 = *(const uint4*)(Bs + ((nb + s1i) * 16 + k32 + 1) * 512 + o1);
        }
        __syncthreads();
        const u16* asrc = (k32 < 8) ? (pa + k32 * 32) : (ph + (k32 - 8) * 32);
        bf16x8 af = __builtin_bit_cast(bf16x8, *(const uint4*)(asrc + g * 8));
        #pragma unroll
        for (int nt = 0; nt < 8; nt++){
            bf16x8 bfr = __builtin_bit_cast(bf16x8, *(const uint4*)(&ldsB[(nt * 64 + lane) * 8]));
            acc[nt] = __builtin_amdgcn_mfma_f32_16x16x32_bf16(af, bfr, acc[nt], 0, 0, 0);
        }
    }
    #pragma unroll
    for (int nt = 0; nt < 8; nt++){
        int n = (nb + nt) * 16 + ml;
        float bn = bias[n];
        #pragma unroll
        for (int r = 0; r < 4; r++){
            int rowg = m0 + g * 4 + r;
            if (rowg < NN){
                float v = acc[nt][r] + bn;
                out[(size_t)rowg * 256 + n] = f2b(v > 0.f ? v : 0.f);
            }
        }
    }
}

// ---------------- node-level P GEMM: P = bf16( h@[W1a|W1b] + base ), base = b1 + td*w513 on Pa cols ----------------
__global__ __launch_bounds__(256) void k_gemm_p(const u16* __restrict__ hin,
    const u16* __restrict__ Bc, const float* __restrict__ b1, const float* __restrict__ W1tail,
    const float* __restrict__ tdp, u16* __restrict__ P){
    __shared__ __align__(16) u16 ldsB[4096];   // 8 KB: one k32-chunk, 8 local ntiles
    int t = threadIdx.x, wave = t >> 6, lane = t & 63;
    int m0 = blockIdx.x * 64 + wave * 16;
    int nb = blockIdx.y * 8;                   // global ntile base (0..31 total)
    int ml = lane & 15, g = lane >> 4;
    int arow = m0 + ml; if (arow > NN - 1) arow = NN - 1;
    const u16* ph = hin + (size_t)arow * 256;
    float td = tdp[0];

    int flat0 = t * 8, flat1 = (256 + t) * 8;
    int s0i = flat0 >> 9, o0 = flat0 & 511;
    int s1i = flat1 >> 9, o1 = flat1 & 511;
    uint4 p0 = *(const uint4*)(Bc + ((nb + s0i) * 8 + 0) * 512 + o0);
    uint4 p1 = *(const uint4*)(Bc + ((nb + s1i) * 8 + 0) * 512 + o1);

    f32x4 acc[8] = {};
    for (int k32 = 0; k32 < 8; k32++){
        __syncthreads();
        *(uint4*)(&ldsB[s0i * 512 + o0]) = p0;
        *(uint4*)(&ldsB[s1i * 512 + o1]) = p1;
        if (k32 < 7){
            p0 = *(const uint4*)(Bc + ((nb + s0i) * 8 + k32 + 1) * 512 + o0);
            p1 = *(const uint4*)(Bc + ((nb + s1i) * 8 + k32 + 1) * 512 + o1);
        }
        __syncthreads();
        bf16x8 af = __builtin_bit_cast(bf16x8, *(const uint4*)(ph + k32 * 32 + g * 8));
        #pragma unroll
        for (int nt = 0; nt < 8; nt++){
            bf16x8 bfr = __builtin_bit_cast(bf16x8, *(const uint4*)(&ldsB[(nt * 64 + lane) * 8]));
            acc[nt] = __builtin_amdgcn_mfma_f32_16x16x32_bf16(af, bfr, acc[nt], 0, 0, 0);
        }
    }
    #pragma unroll
    for (int nt = 0; nt < 8; nt++){
        int n = (nb + nt) * 16 + ml;                       // 0..511
        float base = (n < 256) ? (b1[n] + td * W1tail[256 + n]) : 0.f;
        #pragma unroll
        for (int r = 0; r < 4; r++){
            int rowg = m0 + g * 4 + r;
            if (rowg < NN) P[(size_t)rowg * 512 + n] = f2b(acc[nt][r] + base);
        }
    }
}

// ---------------- edge kernel (CSR-ordered, bf16 P): z1 = relu(Pa[src]+Pb[col]+ea*w512) -> GEMM2 -> W3 dot ----------------
__global__ __launch_bounds__(256) void k_edge(const u16* __restrict__ P,
    const int4* __restrict__ meta, const float* __restrict__ W1tail,
    const u16* __restrict__ B2s, const float* __restrict__ b2v,
    const float* __restrict__ W3, const float* __restrict__ b3, float* __restrict__ out){
    __shared__ __align__(16) u16 ldsX[4096];    // 8 KB: one B2 k32-chunk
    __shared__ __align__(16) u16 ldsZ[16384];   // 32 KB: z1, per-wave 16 x 256, xor-swizzled
    int t = threadIdx.x, wave = t >> 6, lane = t & 63;
    int m0 = blockIdx.x * 64;
    int half = lane >> 5, cl = lane & 31;
    int c0 = cl * 8;

    float wv[8];
    #pragma unroll
    for (int j = 0; j < 8; j++) wv[j] = W1tail[c0 + j];

    #pragma unroll
    for (int it = 0; it < 8; it += 2){
        int rA = it * 2 + half;
        int rB = it * 2 + 2 + half;
        int sA = m0 + wave * 16 + rA; if (sA > NE - 1) sA = NE - 1;
        int sB = m0 + wave * 16 + rB; if (sB > NE - 1) sB = NE - 1;
        int4 mA = meta[sA];
        int4 mB = meta[sB];
        const u16* paA = P + (size_t)mA.x * 512;
        const u16* pbA = P + (size_t)mA.y * 512 + 256;
        const u16* paB = P + (size_t)mB.x * 512;
        const u16* pbB = P + (size_t)mB.y * 512 + 256;
        float eA = __builtin_bit_cast(float, mA.w);
        float eB = __builtin_bit_cast(float, mB.w);
        uint4 vaA = *(const uint4*)(paA + c0);
        uint4 vbA = *(const uint4*)(pbA + c0);
        uint4 vaB = *(const uint4*)(paB + c0);
        uint4 vbB = *(const uint4*)(pbB + c0);
        float v0, v1, v2, v3, v4, v5, v6, v7;
        uint4 st;
        v0 = b2f((u16)vaA.x) + b2f((u16)vbA.x) + eA * wv[0];
        v1 = b2f((u16)(vaA.x >> 16)) + b2f((u16)(vbA.x >> 16)) + eA * wv[1];
        v2 = b2f((u16)vaA.y) + b2f((u16)vbA.y) + eA * wv[2];
        v3 = b2f((u16)(vaA.y >> 16)) + b2f((u16)(vbA.y >> 16)) + eA * wv[3];
        v4 = b2f((u16)vaA.z) + b2f((u16)vbA.z) + eA * wv[4];
        v5 = b2f((u16)(vaA.z >> 16)) + b2f((u16)(vbA.z >> 16)) + eA * wv[5];
        v6 = b2f((u16)vaA.w) + b2f((u16)vbA.w) + eA * wv[6];
        v7 = b2f((u16)(vaA.w >> 16)) + b2f((u16)(vbA.w >> 16)) + eA * wv[7];
        v0 = v0 > 0.f ? v0 : 0.f; v1 = v1 > 0.f ? v1 : 0.f;
        v2 = v2 > 0.f ? v2 : 0.f; v3 = v3 > 0.f ? v3 : 0.f;
        v4 = v4 > 0.f ? v4 : 0.f; v5 = v5 > 0.f ? v5 : 0.f;
        v6 = v6 > 0.f ? v6 : 0.f; v7 = v7 > 0.f ? v7 : 0.f;
        st.x = (u32)f2b(v0) | ((u32)f2b(v1) << 16);
        st.y = (u32)f2b(v2) | ((u32)f2b(v3) << 16);
        st.z = (u32)f2b(v4) | ((u32)f2b(v5) << 16);
        st.w = (u32)f2b(v6) | ((u32)f2b(v7) << 16);
        *(uint4*)(&ldsZ[wave * 4096 + rA * 256 + ((cl ^ (rA & 7)) << 3)]) = st;
        v0 = b2f((u16)vaB.x) + b2f((u16)vbB.x) + eB * wv[0];
        v1 = b2f((u16)(vaB.x >> 16)) + b2f((u16)(vbB.x >> 16)) + eB * wv[1];
        v2 = b2f((u16)vaB.y) + b2f((u16)vbB.y) + eB * wv[2];
        v3 = b2f((u16)(vaB.y >> 16)) + b2f((u16)(vbB.y >> 16)) + eB * wv[3];
        v4 = b2f((u16)vaB.z) + b2f((u16)vbB.z) + eB * wv[4];
        v5 = b2f((u16)(vaB.z >> 16)) + b2f((u16)(vbB.z >> 16)) + eB * wv[5];
        v6 = b2f((u16)vaB.w) + b2f((u16)vbB.w) + eB * wv[6];
        v7 = b2f((u16)(vaB.w >> 16)) + b2f((u16)(vbB.w >> 16)) + eB * wv[7];
        v0 = v0 > 0.f ? v0 : 0.f; v1 = v1 > 0.f ? v1 : 0.f;
        v2 = v2 > 0.f ? v2 : 0.f; v3 = v3 > 0.f ? v3 : 0.f;
        v4 = v4 > 0.f ? v4 : 0.f; v5 = v5 > 0.f ? v5 : 0.f;
        v6 = v6 > 0.f ? v6 : 0.f; v7 = v7 > 0.f ? v7 : 0.f;
        st.x = (u32)f2b(v0) | ((u32)f2b(v1) << 16);
        st.y = (u32)f2b(v2) | ((u32)f2b(v3) << 16);
        st.z = (u32)f2b(v4) | ((u32)f2b(v5) << 16);
        st.w = (u32)f2b(v6) | ((u32)f2b(v7) << 16);
        *(uint4*)(&ldsZ[wave * 4096 + rB * 256 + ((cl ^ (rB & 7)) << 3)]) = st;
    }

    int ml = lane & 15, g = lane >> 4;
    int nt0 = t >> 6, off0 = (t & 63) * 8;
    f32x4 acc2[8] = {};
    uint4 q0 = *(const uint4*)(B2s + (nt0 * 8 + 0) * 512 + off0);
    uint4 q1 = *(const uint4*)(B2s + ((nt0 + 4) * 8 + 0) * 512 + off0);
    for (int kc = 0; kc < 8; kc++){
        __syncthreads();
        *(uint4*)(&ldsX[nt0 * 512 + off0]) = q0;
        *(uint4*)(&ldsX[(nt0 + 4) * 512 + off0]) = q1;
        if (kc < 7){
            q0 = *(const uint4*)(B2s + (nt0 * 8 + kc + 1) * 512 + off0);
            q1 = *(const uint4*)(B2s + ((nt0 + 4) * 8 + kc + 1) * 512 + off0);
        }
        __syncthreads();
        int kb = kc * 4 + g;
        bf16x8 af = __builtin_bit_cast(bf16x8, *(const uint4*)(&ldsZ[wave * 4096 + ml * 256 + ((kb ^ (ml & 7)) << 3)]));
        #pragma unroll
        for (int nt = 0; nt < 8; nt++){
            bf16x8 bfr = __builtin_bit_cast(bf16x8, *(const uint4*)(&ldsX[(nt * 64 + lane) * 8]));
            acc2[nt] = __builtin_amdgcn_mfma_f32_16x16x32_bf16(af, bfr, acc2[nt], 0, 0, 0);
        }
    }
    float s0 = 0.f, s1 = 0.f, s2 = 0.f, s3 = 0.f;
    #pragma unroll
    for (int nt = 0; nt < 8; nt++){
        int n = nt * 16 + ml;
        float bn = b2v[n];
        float w3 = W3[n];
        float z;
        z = acc2[nt][0] + bn; s0 += (z > 0.f ? z : 0.f) * w3;
        z = acc2[nt][1] + bn; s1 += (z > 0.f ? z : 0.f) * w3;
        z = acc2[nt][2] + bn; s2 += (z > 0.f ? z : 0.f) * w3;
        z = acc2[nt][3] + bn; s3 += (z > 0.f ? z : 0.f) * w3;
    }
    #pragma unroll
    for (int d = 1; d < 16; d <<= 1){
        s0 += __shfl_xor(s0, d); s1 += __shfl_xor(s1, d);
        s2 += __shfl_xor(s2, d); s3 += __shfl_xor(s3, d);
    }
    if (ml == 0){
        float bb = b3[0];
        int sb = m0 + wave * 16 + g * 4;
        const int* mz = (const int*)meta;
        if (sb + 0 < NE) out[mz[(sb + 0) * 4 + 2]] = s0 + bb;
        if (sb + 1 < NE) out[mz[(sb + 1) * 4 + 2]] = s1 + bb;
        if (sb + 2 < NE) out[mz[(sb + 2) * 4 + 2]] = s2 + bb;
        if (sb + 3 < NE) out[mz[(sb + 3) * 4 + 2]] = s3 + bb;
    }
}

__global__ void k_fillcode_f32(float* __restrict__ out, float c){
    int i = blockIdx.x * 256 + threadIdx.x;
    if (i < NE) out[i] = c;
}

extern "C" void kernel_launch(void* const* d_in, const int* in_sizes, int n_in,
                              void* d_out, int out_size, void* d_ws, size_t ws_size,
                              hipStream_t stream){
    float* out = (float*)d_out;

    static const int exp_sizes[19] = {60000,600000,300000,1,768,256,768,65536,256,65536,
                                      65536,256,65536,131584,256,32768,128,128,1};
    int bad = -1;
    if (n_in != 19) bad = 19;
    else for (int k = 0; k < 19; k++) if (in_sizes[k] != exp_sizes[k]){ bad = k; break; }
    if (bad >= 0){
        k_fillcode_f32<<<(NE + 255) / 256, 256, 0, stream>>>(out, 1000.f + 50.f * bad);
        return;
    }

    char* ws = (char*)d_ws;
    size_t off = 0;
    auto alloc = [&](size_t bytes) -> void* {
        void* p = ws + off;
        off += (bytes + 255) & ~(size_t)255;
        return p;
    };
    int*   deg   = (int*)alloc(NN * 4);
    int*   cur   = (int*)alloc(NN * 4);
    int*   offs  = (int*)alloc((NN + 1) * 4);
    float* invd  = (float*)alloc(NN * 4);
    int*   srcs  = (int*)alloc(NE * 4);
    int4*  meta  = (int4*)alloc((size_t)NE * 16);
    u16*   h1b   = (u16*)alloc((size_t)NN * 256 * 2);
    u16*   h2b   = (u16*)alloc((size_t)NN * 256 * 2);
    u16*   h3b   = (u16*)alloc((size_t)NN * 256 * 2);
    u16*   aggb  = (u16*)alloc((size_t)NN * 256 * 2);
    u16*   WLs2  = (u16*)alloc(512 * 256 * 2);
    u16*   WLs3  = (u16*)alloc(512 * 256 * 2);
    u16*   Bcat  = (u16*)alloc(512 * 256 * 2);
    u16*   B2s   = (u16*)alloc(256 * 128 * 2);
    u16*   Pbuf  = (u16*)alloc((size_t)NN * 512 * 2);   // 20.5 MB: [Pa|Pb] bf16
    if (off > ws_size){
        k_fillcode_f32<<<(NE + 255) / 256, 256, 0, stream>>>(out, 9000.f);
        return;
    }

    const float* x   = (const float*)d_in[0];
    const int*   ei  = (const int*)d_in[1];     // (2,E) int32: [row..., col...]
    const float* ea  = (const float*)d_in[2];
    const float* td  = (const float*)d_in[3];
    const float* Wl1 = (const float*)d_in[4];
    const float* bl1 = (const float*)d_in[5];
    const float* Wr1 = (const float*)d_in[6];
    const float* Wl2 = (const float*)d_in[7];
    const float* bl2 = (const float*)d_in[8];
    const float* Wr2 = (const float*)d_in[9];
    const float* Wl3 = (const float*)d_in[10];
    const float* bl3 = (const float*)d_in[11];
    const float* Wr3 = (const float*)d_in[12];
    const float* W1  = (const float*)d_in[13];
    const float* b1  = (const float*)d_in[14];
    const float* W2  = (const float*)d_in[15];
    const float* b2  = (const float*)d_in[16];
    const float* W3  = (const float*)d_in[17];
    const float* b3  = (const float*)d_in[18];

    hipMemsetAsync(deg, 0, (size_t)((char*)cur - (char*)deg) + NN * 4, stream);

    const int* rowv = ei;          // sources
    const int* colv = ei + NE;     // targets

    // weight swizzles + degree count in one launch (count needs the memset above)
    k_swz_cnt<<<2836, 256, 0, stream>>>(Wl2, Wr2, Wl3, Wr3, W1, W2, WLs2, WLs3, Bcat, B2s, colv, deg);
    k_scan <<<1, 1024, 0, stream>>>(deg, offs, invd);
    k_fill <<<(NE + 255) / 256, 256, 0, stream>>>(rowv, colv, ea, offs, cur, srcs, meta);

    // SAGE layer 1 (fp32 math, bf16 out)
    k_layer1<<<NN / 4, 256, 0, stream>>>(x, offs, srcs, invd, Wl1, bl1, Wr1, h1b);

    dim3 ggrid((NN + 63) / 64, 2);

    // SAGE layers 2,3: high-TLP aggr + LDS-staged N-split GEMM (round-11 proven)
    k_aggr<<<NN / 4, 256, 0, stream>>>(h1b, offs, srcs, invd, aggb);
    k_gemm_node<<<ggrid, 256, 0, stream>>>(aggb, h1b, WLs2, bl2, h2b);

    k_aggr<<<NN / 4, 256, 0, stream>>>(h2b, offs, srcs, invd, aggb);
    k_gemm_node<<<ggrid, 256, 0, stream>>>(aggb, h2b, WLs3, bl3, h3b);

    // node-level P = bf16(h3 @ [W1a|W1b] + base), LDS-staged
    dim3 pgrid((NN + 63) / 64, 4);
    k_gemm_p<<<pgrid, 256, 0, stream>>>(h3b, Bcat, b1, W1 + 512 * 256, td, Pbuf);

    // edge kernel (CSR order, 64 edges/block, bf16 P)
    k_edge<<<(NE + 63) / 64, 256, 0, stream>>>(Pbuf, meta, W1 + 512 * 256,
                                               B2s, b2, W3, b3, out);
}